// Round 7
// baseline (13.288 us; speedup 1.0000x reference)
//
#include <hip/hip_runtime.h>

// upsample_nn: values [C=64, N=4096] f32, coords [N,2] f32 in [0,1)
// out [C, 4N]: first N cols = values, next 3N cols = values[:, argmin_j d2(g,j)]
//
// Reference d2 semantics (verified bit-exact R3-R6, contraction OFF):
//   qx = (x [+0.001f]) - 0.0005f   (f32, per variant)
//   qq = qx*qx + qy*qy ; cc = cx*cx + cy*cy          (plain mul/add)
//   qc = fmaf(qy, cy, qx*cx)                          (K=2 FMA dot)
//   d2 = (qq + cc) - (qc + qc)
//   argmin = first occurrence -> lexicographic (d2, idx) min (order-free)
//
// Window proof (R4, unchanged): any winner/tie has exact distance <= 2.55e-3
// < R = 3.5e-3; a GD x GD grid searched over [q-R, q+R] cells (floor is
// monotone; index slack 0.95e-3*GD >> fp rounding) contains all winners.
// GD=32: window spans <=2 cells/dim, avg ~6 candidates/query.
//
// R6 lesson: build critical path (7 barriers, 3 LDS passes over the points)
// dominates device time. This version: points live in VGPRs across
// bin->scatter, the 1024-cell scan runs in wave 0 only (no cross-wave
// handoff), sorted coords+ids stored for single-hop eval. 4 barriers total.
// Counting sort retained => no overflow path, deterministic argmin.

#pragma clang fp contract(off)

constexpr int   Nn    = 4096;
constexpr int   Cc    = 64;
constexpr int   NQ    = 3 * Nn;          // 12288
constexpr int   GD    = 32;              // cell grid dim (cell = 1/32)
constexpr int   NCELL = GD * GD;         // 1024
constexpr float Rm    = 3.5e-3f;
constexpr int   QPB   = 64;              // queries per block
constexpr int   QBLK  = NQ / QPB;        // 192 query blocks
constexpr int   NBLK  = QBLK + 64;       // + 64 copy blocks = 256

__global__ __launch_bounds__(256) void upsample_fused_kernel(
    const float* __restrict__ values,   // [Cc][Nn]
    const float* __restrict__ coords,   // [Nn][2]
    float* __restrict__ out)            // [Cc][4*Nn]
{
#pragma clang fp contract(off)
    __shared__ int            sCnt[NCELL];   // 4 KB  counts -> starts -> cursors
    __shared__ float2         sPts[Nn];      // 32 KB cell-sorted coords
    __shared__ unsigned short sIds[Nn];      // 8 KB  cell-sorted original ids
    __shared__ int            sBi[QPB];      // resolved argmin per query

    const int tid = threadIdx.x;

    // ---------------- copy blocks: values -> out[:, 0:Nn] ----------------
    if (blockIdx.x >= QBLK) {
        int b = blockIdx.x - QBLK;           // 0..63 ; 65536 float4 total
        #pragma unroll
        for (int k = 0; k < 4; ++k) {
            int gi  = b * 1024 + k * 256 + tid;
            int row = gi >> 10;              // values: 1024 float4 per row
            int c4  = gi & 1023;
            float4 v = reinterpret_cast<const float4*>(values)[row * 1024 + c4];
            reinterpret_cast<float4*>(out)[row * 4096 + c4] = v; // 4096 f4/row
        }
        return;
    }

    // ---- prefetch this lane's query-source coords (hides under build) ----
    const int q    = blockIdx.x * QPB + (tid & 63);  // global query id
    const int isrc = q & (Nn - 1);
    float2 ci = make_float2(0.f, 0.f);
    if (tid < QPB) ci = reinterpret_cast<const float2*>(coords)[isrc];

    // ---------------- P0: zero counts + load 16 pts to regs + bin ---------
    #pragma unroll
    for (int k = 0; k < NCELL / 256; ++k) sCnt[tid + 256 * k] = 0;

    float2 pt[16];
    int    cell[16];
    #pragma unroll
    for (int k = 0; k < 8; ++k) {            // 8 float4 = 16 points
        int t4 = tid + 256 * k;              // [0, 2048)
        float4 v = reinterpret_cast<const float4*>(coords)[t4];
        pt[2 * k]     = make_float2(v.x, v.y);
        pt[2 * k + 1] = make_float2(v.z, v.w);
    }
    __syncthreads();                         // counts zeroed before atomics
    #pragma unroll
    for (int k = 0; k < 16; ++k) {
        int cx = min(GD - 1, (int)(pt[k].x * (float)GD));  // [0,1): trunc=floor
        int cy = min(GD - 1, (int)(pt[k].y * (float)GD));
        cell[k] = cy * GD + cx;
        atomicAdd(&sCnt[cell[k]], 1);
    }
    __syncthreads();

    // ---------------- P1: exclusive scan of 1024 counts (wave 0 only) -----
    if (tid < 64) {
        int loc[16];
        int run = 0;
        #pragma unroll
        for (int k = 0; k < 16; ++k) { loc[k] = run; run += sCnt[tid * 16 + k]; }
        int inc = run;
        #pragma unroll
        for (int off = 1; off < 64; off <<= 1) {
            int nv = __shfl_up(inc, off, 64);
            if (tid >= off) inc += nv;
        }
        const int excl = inc - run;          // exclusive start of lane's cells
        #pragma unroll
        for (int k = 0; k < 16; ++k) sCnt[tid * 16 + k] = excl + loc[k];
    }
    __syncthreads();

    // ---------------- P2: scatter from regs (counting sort) ---------------
    #pragma unroll
    for (int k = 0; k < 16; ++k) {
        int pos = atomicAdd(&sCnt[cell[k]], 1);
        int j   = ((tid + 256 * (k >> 1)) << 1) | (k & 1);  // original id
        sPts[pos] = pt[k];
        sIds[pos] = (unsigned short)j;
    }
    __syncthreads();
    // sCnt[cell] = end cursor; start(cell) = (cell==0 ? 0 : sCnt[cell-1])

    // ---------------- P3: 64 queries, one per lane of wave 0 --------------
    if (tid < QPB) {
        const int var = q >> 12;             // variant 0/1/2
        const float x = ci.x, y = ci.y;
        float qx, qy;
        if (var == 0) {                      // (x, y+sy) - shift
            qx = x - 0.0005f;
            qy = (y + 0.001f) - 0.0005f;
        } else if (var == 1) {               // (x+sx, y) - shift
            qx = (x + 0.001f) - 0.0005f;
            qy = y - 0.0005f;
        } else {                             // (x+sx, y+sy) - shift
            qx = (x + 0.001f) - 0.0005f;
            qy = (y + 0.001f) - 0.0005f;
        }
        const float qq = qx * qx + qy * qy;  // contract(off): plain

        const int xlo = max(0, (int)floorf((qx - Rm) * (float)GD));
        const int xhi = min(GD - 1, (int)floorf((qx + Rm) * (float)GD));
        const int ylo = max(0, (int)floorf((qy - Rm) * (float)GD));
        const int yhi = min(GD - 1, (int)floorf((qy + Rm) * (float)GD));

        float bd = INFINITY;
        int   bi = 0x7fffffff;
        for (int cy = ylo; cy <= yhi; ++cy) {
            int cellLo = cy * GD + xlo;
            int cellHi = cy * GD + xhi;
            int s = (cellLo == 0) ? 0 : sCnt[cellLo - 1];
            int e = sCnt[cellHi];            // contiguous row range
            for (int p = s; p < e; ++p) {
                float2 c  = sPts[p];
                int    jj = sIds[p];
                float  cc = c.x * c.x + c.y * c.y;
                float  qc = __builtin_fmaf(qy, c.y, qx * c.x);
                float  d2 = (qq + cc) - (qc + qc);
                if (d2 < bd || (d2 == bd && jj < bi)) { bd = d2; bi = jj; }
            }
        }
        sBi[tid] = bi;
    }
    __syncthreads();

    // ---------------- P4: gather + write, all 256 threads -----------------
    // lane group cg=tid>>6 owns 16 channels; 64 lanes = 64 queries -> 256B
    // coalesced writes.
    {
        const int ql = tid & 63;
        const int cg = tid >> 6;
        const int bi = sBi[ql];
        const int q0 = blockIdx.x * QPB;
        #pragma unroll
        for (int k = 0; k < 16; ++k) {
            int ch = cg * 16 + k;
            out[(size_t)ch * (4 * Nn) + Nn + q0 + ql] = values[ch * Nn + bi];
        }
    }
}

extern "C" void kernel_launch(void* const* d_in, const int* in_sizes, int n_in,
                              void* d_out, int out_size, void* d_ws, size_t ws_size,
                              hipStream_t stream) {
    const float* values = (const float*)d_in[0];  // [64, 4096] f32
    const float* coords = (const float*)d_in[1];  // [4096, 2] f32
    float* out = (float*)d_out;                   // [64, 16384] f32
    hipLaunchKernelGGL(upsample_fused_kernel, dim3(NBLK), dim3(256), 0, stream,
                       values, coords, out);
}

// Round 8
// 10.924 us; speedup vs baseline: 1.2165x; 1.2165x over previous
//
#include <hip/hip_runtime.h>

// upsample_nn: values [C=64, N=4096] f32, coords [N,2] f32 in [0,1)
// out [C, 4N]: first N cols = values, next 3N cols = values[:, argmin_j d2(g,j)]
//
// Reference d2 semantics (verified bit-exact R3-R7, contraction OFF):
//   qx = (x [+0.001f]) - 0.0005f   (f32, per variant)
//   qq = qx*qx + qy*qy ; cc = cx*cx + cy*cy          (plain mul/add)
//   qc = fmaf(qy, cy, qx*cx)                          (K=2 FMA dot)
//   d2 = (qq + cc) - (qc + qc)
//   argmin = first occurrence -> lexicographic (d2, idx) min (order-free)
//
// Window proof (R4, unchanged): any winner/tie has exact distance <= 2.55e-3
// < R = 3.5e-3; a GD x GD grid searched over [q-R, q+R] cells (floor
// monotone; slack 0.95e-3*GD >> fp rounding) contains all winners. GD=32:
// window spans <=2 cells/dim, avg ~6 candidates/query.
//
// R7 lesson: build micro-opts are invisible (~2 us total device work left,
// ~11 us fixed launch overhead). Only parallelism spread has moved the
// needle. This version: 192 UNIFORM blocks (copy folded in as grid-stride,
// overlapping the build) and 4-lane-per-query eval (all 256 threads active;
// shfl_xor lexicographic reduce -> argmin provably unchanged).

#pragma clang fp contract(off)

constexpr int   Nn    = 4096;
constexpr int   Cc    = 64;
constexpr int   NQ    = 3 * Nn;          // 12288
constexpr int   GD    = 32;              // cell grid dim (cell = 1/32)
constexpr int   NCELL = GD * GD;         // 1024
constexpr float Rm    = 3.5e-3f;
constexpr int   QPB   = 64;              // queries per block
constexpr int   QBLK  = NQ / QPB;        // 192 blocks (uniform)

__global__ __launch_bounds__(256) void upsample_fused_kernel(
    const float* __restrict__ values,   // [Cc][Nn]
    const float* __restrict__ coords,   // [Nn][2]
    float* __restrict__ out)            // [Cc][4*Nn]
{
#pragma clang fp contract(off)
    __shared__ int            sCnt[NCELL];   // 4 KB  counts -> starts -> cursors
    __shared__ float2         sPts[Nn];      // 32 KB cell-sorted coords
    __shared__ unsigned short sIds[Nn];      // 8 KB  cell-sorted original ids
    __shared__ int            sBi[QPB];      // resolved argmin per query

    const int tid = threadIdx.x;

    // ---- ride-along copy: values -> out[:, 0:Nn], grid-stride float4 ----
    // (independent of all LDS phases; overlaps the build)
    for (int t = blockIdx.x * 256 + tid; t < Cc * (Nn / 4); t += QBLK * 256) {
        int row = t >> 10;                   // values: 1024 float4 per row
        int c4  = t & 1023;
        float4 v = reinterpret_cast<const float4*>(values)[row * 1024 + c4];
        reinterpret_cast<float4*>(out)[row * 4096 + c4] = v; // out: 4096 f4/row
    }

    // ---- per-thread query identity: 4 lanes per query ----
    const int g    = tid >> 2;               // query slot in block [0,64)
    const int l    = tid & 3;                // lane within query group
    const int q    = blockIdx.x * QPB + g;   // global query id [0, 12288)
    const int isrc = q & (Nn - 1);
    const float2 ci = reinterpret_cast<const float2*>(coords)[isrc];

    // ---------------- P0: zero counts + load 16 pts to regs + bin ---------
    #pragma unroll
    for (int k = 0; k < NCELL / 256; ++k) sCnt[tid + 256 * k] = 0;

    float2 pt[16];
    int    cell[16];
    #pragma unroll
    for (int k = 0; k < 8; ++k) {            // 8 float4 = 16 points
        int t4 = tid + 256 * k;              // [0, 2048)
        float4 v = reinterpret_cast<const float4*>(coords)[t4];
        pt[2 * k]     = make_float2(v.x, v.y);
        pt[2 * k + 1] = make_float2(v.z, v.w);
    }
    __syncthreads();                         // counts zeroed before atomics
    #pragma unroll
    for (int k = 0; k < 16; ++k) {
        int cx = min(GD - 1, (int)(pt[k].x * (float)GD));  // [0,1): trunc=floor
        int cy = min(GD - 1, (int)(pt[k].y * (float)GD));
        cell[k] = cy * GD + cx;
        atomicAdd(&sCnt[cell[k]], 1);
    }
    __syncthreads();

    // ---------------- P1: exclusive scan of 1024 counts (wave 0 only) -----
    if (tid < 64) {
        int loc[16];
        int run = 0;
        #pragma unroll
        for (int k = 0; k < 16; ++k) { loc[k] = run; run += sCnt[tid * 16 + k]; }
        int inc = run;
        #pragma unroll
        for (int off = 1; off < 64; off <<= 1) {
            int nv = __shfl_up(inc, off, 64);
            if (tid >= off) inc += nv;
        }
        const int excl = inc - run;          // exclusive start of lane's cells
        #pragma unroll
        for (int k = 0; k < 16; ++k) sCnt[tid * 16 + k] = excl + loc[k];
    }
    __syncthreads();

    // ---------------- P2: scatter from regs (counting sort) ---------------
    #pragma unroll
    for (int k = 0; k < 16; ++k) {
        int pos = atomicAdd(&sCnt[cell[k]], 1);
        int j   = ((tid + 256 * (k >> 1)) << 1) | (k & 1);  // original id
        sPts[pos] = pt[k];
        sIds[pos] = (unsigned short)j;
    }
    __syncthreads();
    // sCnt[cell] = end cursor; start(cell) = (cell==0 ? 0 : sCnt[cell-1])

    // ---------------- P3: eval, 4 lanes per query (all 256 threads) -------
    {
        const int var = q >> 12;             // variant 0/1/2
        const float x = ci.x, y = ci.y;
        float qx, qy;
        if (var == 0) {                      // (x, y+sy) - shift
            qx = x - 0.0005f;
            qy = (y + 0.001f) - 0.0005f;
        } else if (var == 1) {               // (x+sx, y) - shift
            qx = (x + 0.001f) - 0.0005f;
            qy = y - 0.0005f;
        } else {                             // (x+sx, y+sy) - shift
            qx = (x + 0.001f) - 0.0005f;
            qy = (y + 0.001f) - 0.0005f;
        }
        const float qq = qx * qx + qy * qy;  // contract(off): plain

        const int xlo = max(0, (int)floorf((qx - Rm) * (float)GD));
        const int xhi = min(GD - 1, (int)floorf((qx + Rm) * (float)GD));
        const int ylo = max(0, (int)floorf((qy - Rm) * (float)GD));
        const int yhi = min(GD - 1, (int)floorf((qy + Rm) * (float)GD));

        float bd = INFINITY;
        int   bi = 0x7fffffff;
        for (int cy = ylo; cy <= yhi; ++cy) {
            int cellLo = cy * GD + xlo;
            int cellHi = cy * GD + xhi;
            int s = (cellLo == 0) ? 0 : sCnt[cellLo - 1];
            int e = sCnt[cellHi];            // contiguous row range
            for (int p = s + l; p < e; p += 4) {   // lane-strided
                float2 c  = sPts[p];
                int    jj = sIds[p];
                float  cc = c.x * c.x + c.y * c.y;
                float  qc = __builtin_fmaf(qy, c.y, qx * c.x);
                float  d2 = (qq + cc) - (qc + qc);
                if (d2 < bd || (d2 == bd && jj < bi)) { bd = d2; bi = jj; }
            }
        }
        // lexicographic (d2, idx) reduce across the 4-lane group
        #pragma unroll
        for (int off = 1; off < 4; off <<= 1) {
            float od = __shfl_xor(bd, off, 64);
            int   oi = __shfl_xor(bi, off, 64);
            if (od < bd || (od == bd && oi < bi)) { bd = od; bi = oi; }
        }
        if (l == 0) sBi[g] = bi;
    }
    __syncthreads();

    // ---------------- P4: gather + write, all 256 threads -----------------
    // lane group cg=tid>>6 owns 16 channels; 64 lanes = 64 queries -> 256B
    // coalesced writes.
    {
        const int ql = tid & 63;
        const int cg = tid >> 6;
        const int bi = sBi[ql];
        const int q0 = blockIdx.x * QPB;
        #pragma unroll
        for (int k = 0; k < 16; ++k) {
            int ch = cg * 16 + k;
            out[(size_t)ch * (4 * Nn) + Nn + q0 + ql] = values[ch * Nn + bi];
        }
    }
}

extern "C" void kernel_launch(void* const* d_in, const int* in_sizes, int n_in,
                              void* d_out, int out_size, void* d_ws, size_t ws_size,
                              hipStream_t stream) {
    const float* values = (const float*)d_in[0];  // [64, 4096] f32
    const float* coords = (const float*)d_in[1];  // [4096, 2] f32
    float* out = (float*)d_out;                   // [64, 16384] f32
    hipLaunchKernelGGL(upsample_fused_kernel, dim3(QBLK), dim3(256), 0, stream,
                       values, coords, out);
}